// Round 9
// baseline (322.119 us; speedup 1.0000x reference)
//
#include <hip/hip_runtime.h>
#include <math.h>

#define TPB   256
#define SL    64            // per-thread segment length
#define SEGS  16384         // TLEN / SL
#define TLEN  1048576
#define MOFF  1016          // 65047 / 64
#define ROFF  23            // 65047 % 64
#define NEMA  4             // 0: short/pred, 1: short/targ, 2: long/pred, 3: long/targ
#define CPL   256           // segments per lane in pass 2 (SEGS/64)

__device__ __forceinline__ float comp(const float4& v, int m) {
    return m == 0 ? v.x : m == 1 ? v.y : m == 2 ? v.z : v.w;
}

// Pass 1: per-segment UNSCALED EMA aggregates (= EMA value over the segment
// starting from 0). One thread per (row, segment); contiguous aligned loads.
__global__ __launch_bounds__(TPB) void ldr_partials(
    const float* __restrict__ pred, const float* __restrict__ targ,
    float amS, float amL, float* __restrict__ pB, int rows)
{
    const int tid = blockIdx.x * TPB + threadIdx.x;
    const int r = tid / SEGS, m = tid % SEGS;
    const float4* p4 = (const float4*)(pred + (size_t)r * TLEN + (size_t)m * SL);
    const float4* t4 = (const float4*)(targ + (size_t)r * TLEN + (size_t)m * SL);
    float sp = 0.f, st = 0.f, lp = 0.f, lt = 0.f;
    #pragma unroll
    for (int q = 0; q < SL / 4; ++q) {
        float4 u = p4[q], v = t4[q];
        #pragma unroll
        for (int mm = 0; mm < 4; ++mm) {
            float xu = comp(u, mm), xv = comp(v, mm);
            sp = fmaf(amS, sp, xu); lp = fmaf(amL, lp, xu);
            st = fmaf(amS, st, xv); lt = fmaf(amL, lt, xv);
        }
    }
    pB[((size_t)0 * rows + r) * SEGS + m] = sp;
    pB[((size_t)1 * rows + r) * SEGS + m] = st;
    pB[((size_t)2 * rows + r) * SEGS + m] = lp;
    pB[((size_t)3 * rows + r) * SEGS + m] = lt;
}

// Pass 2: carry-in per segment, in-place. Two sweeps per lane (values don't
// fit in regs at CPL=256): sweep 1 computes the lane total, wave-scan gives
// the lane carry, sweep 2 re-reads and rewrites carries.
__global__ __launch_bounds__(64) void ldr_carry(
    float* __restrict__ pB,
    float AcS, float AcSW, float AcL, float AcLW, int rows)
{
    const int g = blockIdx.x;              // E*rows + r
    const int lane = threadIdx.x;
    const bool isShort = g < 2 * rows;
    const float Ac  = isShort ? AcS  : AcL;    // am^SL
    const float AcW = isShort ? AcSW : AcLW;   // am^(SL*CPL)
    float* Bv = pB + (size_t)g * SEGS + (size_t)lane * CPL;
    float B = 0.f;
    for (int mm = 0; mm < CPL; ++mm) B = fmaf(Ac, B, Bv[mm]);
    float incl = B, Ad = AcW;
    #pragma unroll
    for (int d = 1; d < 64; d <<= 1) {
        float pb = __shfl_up(incl, d, 64);
        if (lane >= d) incl = fmaf(Ad, pb, incl);
        Ad *= Ad;
    }
    float carry = __shfl_up(incl, 1, 64);
    if (lane == 0) carry = 0.f;
    for (int mm = 0; mm < CPL; ++mm) {
        float b = Bv[mm];
        Bv[mm] = carry;
        carry = fmaf(Ac, carry, b);
    }
}

// Pass 3: fully thread-independent fused loss. Thread owns long segment m
// (v positions m*64+i). Pairing via 65047 = 1016*64 + 23:
//   i <  23 : u from short seg a=m-1017, element 41+i  (A-stream)
//   i >= 23 : u from short seg b=m-1016, element i-23  (B-stream)
// A-stream is pre-advanced 41 samples from its carry. No shfl scans, no LDS,
// no barriers; one rcp + one log per position:
//   |u - v| = |log( (sp*lt) / (st*lp) )|
__global__ __launch_bounds__(TPB, 4) void ldr_loss(
    const float* __restrict__ pred, const float* __restrict__ targ,
    const float* __restrict__ cin,
    float amS, float amL, float* __restrict__ partial, int rows)
{
    const int tid = blockIdx.x * TPB + threadIdx.x;
    const int lane = threadIdx.x & 63;
    const int r = tid / SEGS, m = tid % SEGS;
    const int a = (m + SEGS - (MOFF + 1)) & (SEGS - 1);
    const int b = (m + SEGS - MOFF) & (SEGS - 1);
    const float* P = pred + (size_t)r * TLEN;
    const float* T = targ + (size_t)r * TLEN;
    const float4* Lp4 = (const float4*)(P + (size_t)m * SL);
    const float4* Lt4 = (const float4*)(T + (size_t)m * SL);
    const float4* Ap4 = (const float4*)(P + (size_t)a * SL);
    const float4* At4 = (const float4*)(T + (size_t)a * SL);
    const float4* Bp4 = (const float4*)(P + (size_t)b * SL);
    const float4* Bt4 = (const float4*)(T + (size_t)b * SL);
    const float* Apf = P + (size_t)a * SL;
    const float* Atf = T + (size_t)a * SL;

    float ylp = cin[((size_t)2 * rows + r) * SEGS + m];
    float ylt = cin[((size_t)3 * rows + r) * SEGS + m];
    float yap = cin[((size_t)0 * rows + r) * SEGS + a];
    float yat = cin[((size_t)1 * rows + r) * SEGS + a];
    float ybp = cin[((size_t)0 * rows + r) * SEGS + b];
    float ybt = cin[((size_t)1 * rows + r) * SEGS + b];

    // Warm A-stream through elements 0..40 (reach state just before elem 41).
    #pragma unroll
    for (int q = 0; q < 10; ++q) {
        float4 u = Ap4[q], v = At4[q];
        #pragma unroll
        for (int mm = 0; mm < 4; ++mm) {
            yap = fmaf(amS, yap, comp(u, mm));
            yat = fmaf(amS, yat, comp(v, mm));
        }
    }
    yap = fmaf(amS, yap, Apf[40]);
    yat = fmaf(amS, yat, Atf[40]);

    float lsum = 0.f;
    float4 bp4 = {0,0,0,0}, bt4 = {0,0,0,0};
    #pragma unroll
    for (int q = 0; q < SL / 4; ++q) {
        float4 lp4 = Lp4[q], lt4 = Lt4[q];
        #pragma unroll
        for (int mm = 0; mm < 4; ++mm) {
            const int i = 4 * q + mm;
            ylp = fmaf(amL, ylp, comp(lp4, mm));
            ylt = fmaf(amL, ylt, comp(lt4, mm));
            float sp, st;
            if (i < ROFF) {
                sp = yap = fmaf(amS, yap, Apf[41 + i]);
                st = yat = fmaf(amS, yat, Atf[41 + i]);
            } else {
                const int jj = i - ROFF;
                if ((jj & 3) == 0) { bp4 = Bp4[jj >> 2]; bt4 = Bt4[jj >> 2]; }
                sp = ybp = fmaf(amS, ybp, comp(bp4, jj & 3));
                st = ybt = fmaf(amS, ybt, comp(bt4, jj & 3));
            }
            lsum += fabsf(__logf(__fdividef(sp * ylt, st * ylp)));
        }
    }

    #pragma unroll
    for (int d = 32; d > 0; d >>= 1) lsum += __shfl_xor(lsum, d, 64);
    if (lane == 0) partial[tid >> 6] = lsum;
}

__global__ void ldr_finalize(const float* __restrict__ partial, int nparts,
                             float* __restrict__ out, double inv_n)
{
    __shared__ double sd[256];
    double s = 0.0;
    for (int i = threadIdx.x; i < nparts; i += 256) s += (double)partial[i];
    sd[threadIdx.x] = s;
    __syncthreads();
    for (int d = 128; d > 0; d >>= 1) {
        if (threadIdx.x < d) sd[threadIdx.x] += sd[threadIdx.x + d];
        __syncthreads();
    }
    if (threadIdx.x == 0) out[0] = (float)(sd[0] * inv_n);
}

extern "C" void kernel_launch(void* const* d_in, const int* in_sizes, int n_in,
                              void* d_out, int out_size, void* d_ws, size_t ws_size,
                              hipStream_t stream)
{
    const float* pred = (const float*)d_in[0];
    const float* targ = (const float*)d_in[1];
    const int n = in_sizes[0];
    const int rows = n / TLEN;   // 16

    const double csd = 1.0 - exp(-2200.0 / (50.0 * 44100.0));
    const double cld = 1.0 - exp(-2200.0 / (3000.0 * 44100.0));
    const double amSd = 1.0 - csd, amLd = 1.0 - cld;
    const float amS = (float)amSd, amL = (float)amLd;
    const float AcS  = (float)pow(amSd, (double)SL);
    const float AcSW = (float)pow(amSd, (double)SL * CPL);
    const float AcL  = (float)pow(amLd, (double)SL);
    const float AcLW = (float)pow(amLd, (double)SL * CPL);

    // ws layout: [0,256): reserved; pB = NEMA*rows*SEGS floats (4 MB for
    // rows=16), becomes the carry-in table in-place; then partial floats.
    char* wsb = (char*)d_ws;
    float* pB      = (float*)(wsb + 256);
    float* partial = pB + (size_t)NEMA * rows * SEGS;

    const int nthreads = rows * SEGS;          // 262144
    const int nblocks  = nthreads / TPB;       // 1024
    const int nparts   = nthreads / 64;        // 4096

    ldr_partials<<<nblocks, TPB, 0, stream>>>(pred, targ, amS, amL, pB, rows);
    ldr_carry<<<NEMA * rows, 64, 0, stream>>>(pB, AcS, AcSW, AcL, AcLW, rows);
    ldr_loss<<<nblocks, TPB, 0, stream>>>(pred, targ, pB, amS, amL, partial, rows);

    const double inv_n = 1.0 / ((double)rows * (double)TLEN);
    ldr_finalize<<<1, 256, 0, stream>>>(partial, nparts, (float*)d_out, inv_n);
}

// Round 10
// 106.824 us; speedup vs baseline: 3.0154x; 3.0154x over previous
//
#include <hip/hip_runtime.h>
#include <math.h>

#define TPB   256
#define SL    16             // per-thread segment length
#define SEGS  65536          // TLEN / SL (per row)
#define TLEN  1048576
#define MOFF  4065           // 65047 / 16
#define ROFF  7              // 65047 % 16
#define NEMA  4              // 0: short/pred, 1: short/targ, 2: long/pred, 3: long/targ
#define RPT   256            // segs per thread in pass 2 (SEGS / TPB)

__device__ __forceinline__ float comp(const float4& v, int m) {
    return m == 0 ? v.x : m == 1 ? v.y : m == 2 ? v.z : v.w;
}

// integer power by repeated squaring, deterministic
__device__ __forceinline__ float ipowf(float base, int e) {
    float r = 1.0f, p = base;
    while (e) { if (e & 1) r *= p; p *= p; e >>= 1; }
    return r;
}

// Pass 1: per-16-sample-segment UNSCALED EMA aggregates (EMA from 0).
// Lane stride 64 B; each lane's 4 quads consume exactly one cache line.
__global__ __launch_bounds__(TPB) void ldr_partials(
    const float* __restrict__ pred, const float* __restrict__ targ,
    float amS, float amL, float* __restrict__ pB, int rows)
{
    const int tid = blockIdx.x * TPB + threadIdx.x;
    const int r = tid >> 16, m = tid & (SEGS - 1);
    const float4* p4 = (const float4*)(pred + (size_t)r * TLEN + (size_t)m * SL);
    const float4* t4 = (const float4*)(targ + (size_t)r * TLEN + (size_t)m * SL);
    float sp = 0.f, st = 0.f, lp = 0.f, lt = 0.f;
    #pragma unroll
    for (int q = 0; q < SL / 4; ++q) {
        float4 u = p4[q], v = t4[q];
        #pragma unroll
        for (int mm = 0; mm < 4; ++mm) {
            float xu = comp(u, mm), xv = comp(v, mm);
            sp = fmaf(amS, sp, xu); lp = fmaf(amL, lp, xu);
            st = fmaf(amS, st, xv); lt = fmaf(amL, lt, xv);
        }
    }
    const size_t plane = (size_t)rows * SEGS;
    const size_t idx = (size_t)r * SEGS + m;
    pB[0 * plane + idx] = sp;
    pB[1 * plane + idx] = st;
    pB[2 * plane + idx] = lp;
    pB[3 * plane + idx] = lt;
}

// Pass 2: carry-in per segment, in-place. One 256-thread block per (E,r)
// plane; thread j owns RPT consecutive segment aggregates. Off the hot path.
__global__ __launch_bounds__(TPB) void ldr_carry(
    float* __restrict__ pB,
    float AcS, float AcST, float AcSW,
    float AcL, float AcLT, float AcLW, int rows)
{
    __shared__ float slots[4];
    const int g = blockIdx.x;               // E*rows + r
    const int j = threadIdx.x, lane = j & 63, w = j >> 6;
    const bool isShort = g < 2 * rows;
    const float Ac  = isShort ? AcS  : AcL;     // am^SL
    const float AcT = isShort ? AcST : AcLT;    // am^(SL*RPT)
    const float AcW = isShort ? AcSW : AcLW;    // am^(SL*RPT*64)
    float* Bv = pB + (size_t)g * SEGS + (size_t)j * RPT;
    float B = 0.f;
    for (int mm = 0; mm < RPT; ++mm) B = fmaf(Ac, B, Bv[mm]);
    // wave scan over thread aggregates, constant multiplier AcT
    float incl = B, Ad = AcT;
    #pragma unroll
    for (int d = 1; d < 64; d <<= 1) {
        float pb = __shfl_up(incl, d, 64);
        if (lane >= d) incl = fmaf(Ad, pb, incl);
        Ad *= Ad;
    }
    float ex = __shfl_up(incl, 1, 64);
    if (lane == 0) ex = 0.f;
    if (lane == 63) slots[w] = incl;
    __syncthreads();
    float Wc = 0.f;
    for (int u = 0; u < w; ++u) Wc = fmaf(Wc, AcW, slots[u]);
    float carry = fmaf(ipowf(AcT, lane), Wc, ex);
    for (int mm = 0; mm < RPT; ++mm) {
        float old = Bv[mm];
        Bv[mm] = carry;
        carry = fmaf(Ac, carry, old);
    }
}

// Pass 3: fully thread-independent fused loss. Thread owns output positions
// t in [16m, 16m+16): short EMAs at own (aligned) segment m; long EMAs at
// t+65047 -> segs a=m+4065 (elems 7..15, i=0..8) and b=m+4066 (elems 0..6,
// i=9..15), warmed through a's elems 0..6 from a's carry. No shuffle scans
// (except the final reduce), no LDS, no barriers, no atomics.
__global__ __launch_bounds__(TPB) void ldr_loss(
    const float* __restrict__ pred, const float* __restrict__ targ,
    const float* __restrict__ cin,
    float amS, float amL, float* __restrict__ partial, int rows)
{
    const int tid = blockIdx.x * TPB + threadIdx.x;
    const int lane = threadIdx.x & 63;
    const int r = tid >> 16, m = tid & (SEGS - 1);
    const int a = (m + MOFF) & (SEGS - 1);
    const int b = (m + MOFF + 1) & (SEGS - 1);
    const float* P = pred + (size_t)r * TLEN;
    const float* T = targ + (size_t)r * TLEN;
    const size_t plane = (size_t)rows * SEGS;
    const size_t rbase = (size_t)r * SEGS;

    // short EMA values over own segment (static-indexed register array)
    float sp[SL], st[SL];
    {
        const float4* Sp4 = (const float4*)(P + (size_t)m * SL);
        const float4* St4 = (const float4*)(T + (size_t)m * SL);
        float ysp = cin[0 * plane + rbase + m];
        float yst = cin[1 * plane + rbase + m];
        #pragma unroll
        for (int q = 0; q < SL / 4; ++q) {
            float4 u = Sp4[q], v = St4[q];
            #pragma unroll
            for (int mm = 0; mm < 4; ++mm) {
                ysp = fmaf(amS, ysp, comp(u, mm)); sp[4 * q + mm] = ysp;
                yst = fmaf(amS, yst, comp(v, mm)); st[4 * q + mm] = yst;
            }
        }
    }

    float ylp = cin[2 * plane + rbase + a];
    float ylt = cin[3 * plane + rbase + a];
    const float4* Ap4 = (const float4*)(P + (size_t)a * SL);
    const float4* At4 = (const float4*)(T + (size_t)a * SL);
    const float4* Bp4 = (const float4*)(P + (size_t)b * SL);
    const float4* Bt4 = (const float4*)(T + (size_t)b * SL);

    float lsum = 0.f;
    // seg a: warm elems 0..6, loss for elems 7..15 (i = e-7 = 0..8)
    #pragma unroll
    for (int q = 0; q < SL / 4; ++q) {
        float4 u = Ap4[q], v = At4[q];
        #pragma unroll
        for (int mm = 0; mm < 4; ++mm) {
            const int e = 4 * q + mm;
            ylp = fmaf(amL, ylp, comp(u, mm));
            ylt = fmaf(amL, ylt, comp(v, mm));
            if (e >= ROFF) {
                const int i = e - ROFF;
                lsum += fabsf(__logf(__fdividef(sp[i] * ylt, st[i] * ylp)));
            }
        }
    }
    // seg b: elems 0..6, loss for i = e + 9 (9..15)
    #pragma unroll
    for (int q = 0; q < 2; ++q) {
        float4 u = Bp4[q], v = Bt4[q];
        #pragma unroll
        for (int mm = 0; mm < 4; ++mm) {
            const int e = 4 * q + mm;
            if (e < ROFF) {
                ylp = fmaf(amL, ylp, comp(u, mm));
                ylt = fmaf(amL, ylt, comp(v, mm));
                const int i = e + (SL - ROFF);
                lsum += fabsf(__logf(__fdividef(sp[i] * ylt, st[i] * ylp)));
            }
        }
    }

    #pragma unroll
    for (int d = 32; d > 0; d >>= 1) lsum += __shfl_xor(lsum, d, 64);
    if (lane == 0) partial[tid >> 6] = lsum;
}

__global__ void ldr_finalize(const float* __restrict__ partial, int nparts,
                             float* __restrict__ out, double inv_n)
{
    __shared__ double sd[256];
    double s = 0.0;
    for (int i = threadIdx.x; i < nparts; i += 256) s += (double)partial[i];
    sd[threadIdx.x] = s;
    __syncthreads();
    for (int d = 128; d > 0; d >>= 1) {
        if (threadIdx.x < d) sd[threadIdx.x] += sd[threadIdx.x + d];
        __syncthreads();
    }
    if (threadIdx.x == 0) out[0] = (float)(sd[0] * inv_n);
}

extern "C" void kernel_launch(void* const* d_in, const int* in_sizes, int n_in,
                              void* d_out, int out_size, void* d_ws, size_t ws_size,
                              hipStream_t stream)
{
    const float* pred = (const float*)d_in[0];
    const float* targ = (const float*)d_in[1];
    const int n = in_sizes[0];
    const int rows = n / TLEN;   // 16

    const double csd = 1.0 - exp(-2200.0 / (50.0 * 44100.0));
    const double cld = 1.0 - exp(-2200.0 / (3000.0 * 44100.0));
    const double amSd = 1.0 - csd, amLd = 1.0 - cld;
    const float amS = (float)amSd, amL = (float)amLd;
    const float AcS  = (float)pow(amSd, (double)SL);
    const float AcST = (float)pow(amSd, (double)SL * RPT);
    const float AcSW = (float)pow(amSd, (double)SL * RPT * 64.0);
    const float AcL  = (float)pow(amLd, (double)SL);
    const float AcLT = (float)pow(amLd, (double)SL * RPT);
    const float AcLW = (float)pow(amLd, (double)SL * RPT * 64.0);

    // ws layout: [0,256): reserved; pB = NEMA*rows*SEGS floats (16.8 MB for
    // rows=16), becomes the carry-in table in-place; then partial floats.
    char* wsb = (char*)d_ws;
    float* pB      = (float*)(wsb + 256);
    float* partial = pB + (size_t)NEMA * rows * SEGS;

    const int nthreads = rows * SEGS;          // 1048576
    const int nblocks  = nthreads / TPB;       // 4096
    const int nparts   = nthreads / 64;        // 16384

    ldr_partials<<<nblocks, TPB, 0, stream>>>(pred, targ, amS, amL, pB, rows);
    ldr_carry<<<NEMA * rows, TPB, 0, stream>>>(pB, AcS, AcST, AcSW,
                                               AcL, AcLT, AcLW, rows);
    ldr_loss<<<nblocks, TPB, 0, stream>>>(pred, targ, pB, amS, amL, partial, rows);

    const double inv_n = 1.0 / ((double)rows * (double)TLEN);
    ldr_finalize<<<1, 256, 0, stream>>>(partial, nparts, (float*)d_out, inv_n);
}